// Round 2
// baseline (941.332 us; speedup 1.0000x reference)
//
#include <hip/hip_runtime.h>

#define TT   2048
#define CC   256
#define LL   256
#define SS   513          // 2*LL+1
#define NEGF (-1e30f)
#define EPSF (1e-7f)
#define LN2F (0.69314718055994531f)

// One wave per batch. Lane l owns cells s = l*9 + j, j in [0,9).
// Cross-lane dependency per step: previous lane's a[7], a[8] via shfl_up.
// No barriers, no LDS.

__launch_bounds__(64, 1)
__global__ void ctc_wave_kernel(const int* __restrict__ y_true,
                                const float* __restrict__ y_pred,
                                float* __restrict__ out)
{
    const int b    = blockIdx.x;
    const int lane = threadIdx.x;          // 0..63
    const int blank = CC - 1;

    // per-cell label + skip-transition legality
    int  zs[9];
    bool al2[9];
    #pragma unroll
    for (int j = 0; j < 9; ++j) {
        const int s = lane * 9 + j;
        int  z  = blank;
        bool a2 = false;
        if (s < SS && (s & 1)) {
            z = y_true[b * LL + ((s - 1) >> 1)];
            const int zm2 = (s >= 3) ? y_true[b * LL + ((s - 3) >> 1)] : -1;
            a2 = (z != blank) && (z != zm2);
        }
        zs[j] = z; al2[j] = a2;
    }

    const float* base = y_pred + (size_t)b * TT * CC;

    // alpha0 (log2 domain)
    float a[9];
    #pragma unroll
    for (int j = 0; j < 9; ++j) {
        const int s = lane * 9 + j;
        const float p = base[zs[j]];                 // t = 0
        a[j] = (s < 2) ? __builtin_amdgcn_logf(p + EPSF) : NEGF;
    }

    // prefetch steps t=1 (pf0) and t=2 (pf1)
    float pf0[9], pf1[9];
    #pragma unroll
    for (int j = 0; j < 9; ++j) pf0[j] = base[1 * CC + zs[j]];
    #pragma unroll
    for (int j = 0; j < 9; ++j) pf1[j] = base[2 * CC + zs[j]];

#define STEP(PF) do {                                                        \
        float up8 = __shfl_up(a[8], 1);                                      \
        float up7 = __shfl_up(a[7], 1);                                      \
        if (lane == 0) { up8 = NEGF; up7 = NEGF; }                           \
        float om1 = up8, om2 = up7;                                          \
        _Pragma("unroll")                                                    \
        for (int j = 0; j < 9; ++j) {                                        \
            const float old = a[j];                                          \
            const float lp  = __builtin_amdgcn_logf(PF[j] + EPSF);           \
            const float b2  = al2[j] ? om2 : NEGF;                           \
            const float m   = fmaxf(old, fmaxf(om1, b2));                    \
            const float sum = __builtin_amdgcn_exp2f(old - m)                \
                            + __builtin_amdgcn_exp2f(om1 - m)                \
                            + __builtin_amdgcn_exp2f(b2  - m);               \
            a[j] = lp + m + __builtin_amdgcn_logf(sum);                      \
            om2 = om1; om1 = old;                                            \
        }                                                                    \
    } while (0)

    // main loop: steps t and t+1 per iteration; prefetch depth 2
    for (int t = 1; t + 1 < TT; t += 2) {
        float nf0[9], nf1[9];
        // issue next loads first so they overlap the trans work below
        #pragma unroll
        for (int j = 0; j < 9; ++j) nf0[j] = base[(size_t)(t + 2) * CC + zs[j]];
        if (t + 3 < TT) {
            #pragma unroll
            for (int j = 0; j < 9; ++j) nf1[j] = base[(size_t)(t + 3) * CC + zs[j]];
        } else {
            #pragma unroll
            for (int j = 0; j < 9; ++j) nf1[j] = 0.0f;
        }
        STEP(pf0);
        STEP(pf1);
        #pragma unroll
        for (int j = 0; j < 9; ++j) { pf0[j] = nf0[j]; pf1[j] = nf1[j]; }
    }
    // final step t = TT-1 (odd count: 2047 steps total)
    STEP(pf0);
#undef STEP

    // lane 56 holds s=511 (j=7) and s=512 (j=8)
    if (lane == 56) {
        const float x = a[8], y = a[7];
        const float m = fmaxf(x, y);
        const float ll2 = m + __builtin_amdgcn_logf(
                                 __builtin_amdgcn_exp2f(x - m) +
                                 __builtin_amdgcn_exp2f(y - m));
        out[b] = -LN2F * ll2;
    }
}

extern "C" void kernel_launch(void* const* d_in, const int* in_sizes, int n_in,
                              void* d_out, int out_size, void* d_ws, size_t ws_size,
                              hipStream_t stream)
{
    const int*   y_true = (const int*)d_in[0];
    const float* y_pred = (const float*)d_in[1];
    float*       out    = (float*)d_out;
    const int B = in_sizes[0] / LL;   // 32
    ctc_wave_kernel<<<B, 64, 0, stream>>>(y_true, y_pred, out);
}

// Round 3
// 709.949 us; speedup vs baseline: 1.3259x; 1.3259x over previous
//
#include <hip/hip_runtime.h>

#define TT   2048
#define CC   256
#define LL   256
#define SS   513            // 2*LL+1
#define EPSF (1e-7f)
#define LN2F (0.69314718055994531f)
#define EMIN (-(1 << 29))   // "unreachable" exponent sentinel
#define DPTH 5              // prefetch depth (steps ahead)

#if __has_builtin(__builtin_amdgcn_frexp_mantf)
#define FREXP_MANT __builtin_amdgcn_frexp_mantf
#else
static __device__ __forceinline__ float FREXP_MANT(float x){ int e; return frexpf(x,&e); }
#endif
#if __has_builtin(__builtin_amdgcn_frexp_expf)
#define FREXP_EXP __builtin_amdgcn_frexp_expf
#else
static __device__ __forceinline__ int FREXP_EXP(float x){ int e; frexpf(x,&e); return e; }
#endif
#if __has_builtin(__builtin_amdgcn_ldexpf)
#define LDEXP __builtin_amdgcn_ldexpf
#else
#define LDEXP ldexpf
#endif

// One wave per batch. Lane l owns cells s = l*9 + j, j in [0,9).
// alpha[s] kept as extended-range float: value = f * 2^e  (f in [0.5,1) or 0).
// Per-step update is pure full-rate VALU: max / ldexp / add / mul / frexp.
// Cross-lane dep per step: prev lane's cells 7,8 via shfl_up. No LDS/barriers.

__launch_bounds__(64, 1)
__global__ void ctc_ext_kernel(const int* __restrict__ y_true,
                               const float* __restrict__ y_pred,
                               float* __restrict__ out)
{
    const int b     = blockIdx.x;
    const int lane  = threadIdx.x;       // 0..63
    const int blank = CC - 1;

    // per-cell label column + branchless skip-transition masks
    int   zs[9];
    float kill[9];   // 1.0 if skip (s-2 -> s) allowed, else 0.0
    int   bias[9];   // 0 if allowed, else EMIN
    #pragma unroll
    for (int j = 0; j < 9; ++j) {
        const int s = lane * 9 + j;
        int  z  = blank;
        bool a2 = false;
        if (s < SS && (s & 1)) {
            z = y_true[b * LL + ((s - 1) >> 1)];
            const int zm2 = (s >= 3) ? y_true[b * LL + ((s - 3) >> 1)] : -1;
            a2 = (z != blank) && (z != zm2);
        }
        zs[j]   = z;
        kill[j] = a2 ? 1.0f : 0.0f;
        bias[j] = a2 ? 0 : EMIN;
    }

    const float* base = y_pred + (size_t)b * TT * CC;

    // alpha0: s<2 -> p(t=0)+eps, else unreachable
    float f[9]; int e[9];
    #pragma unroll
    for (int j = 0; j < 9; ++j) {
        const int s = lane * 9 + j;
        if (s < 2) {
            const float v = base[zs[j]] + EPSF;
            f[j] = FREXP_MANT(v);
            e[j] = FREXP_EXP(v);
        } else {
            f[j] = 0.0f;
            e[j] = EMIN;
        }
    }

    // rolling prefetch: pf[k] holds the gathered row for step t+k
    float pf[DPTH][9];
    #pragma unroll
    for (int k = 0; k < DPTH; ++k)
        #pragma unroll
        for (int j = 0; j < 9; ++j)
            pf[k][j] = base[(size_t)(1 + k) * CC + zs[j]];

    // one DP step; PV[j] = p+eps for this t. Descending j so the two
    // shfl-dependent cells (j=1,0) come last (hides ds_permute latency).
#define STEP_BODY(PV) do {                                                   \
        float u8f = __shfl_up(f[8], 1), u7f = __shfl_up(f[7], 1);            \
        int   u8e = __shfl_up(e[8], 1), u7e = __shfl_up(e[7], 1);            \
        if (lane == 0) { u8f = 0.0f; u7f = 0.0f; u8e = EMIN; u7e = EMIN; }   \
        _Pragma("unroll")                                                    \
        for (int jj = 8; jj >= 0; --jj) {                                    \
            const float f0 = f[jj];                  const int e0 = e[jj];   \
            const float f1 = (jj >= 1) ? f[jj-1] : u8f;                      \
            const int   e1 = (jj >= 1) ? e[jj-1] : u8e;                      \
            const float f2r = (jj >= 2) ? f[jj-2] : ((jj == 1) ? u8f : u7f); \
            const int   e2r = (jj >= 2) ? e[jj-2] : ((jj == 1) ? u8e : u7e); \
            const float f2 = f2r * kill[jj];                                 \
            const int   e2 = e2r + bias[jj];                                 \
            int E = max(e0, e1); E = max(E, e2);                             \
            const float sum = LDEXP(f0, e0 - E)                              \
                            + LDEXP(f1, e1 - E)                              \
                            + LDEXP(f2, e2 - E);                             \
            const float v = sum * PV[jj];                                    \
            f[jj] = FREXP_MANT(v);                                           \
            e[jj] = E + FREXP_EXP(v);                                        \
        }                                                                    \
    } while (0)

    // main loop: 409 chunks of 5 -> steps t = 1..2045, then 2 tail steps
    int t = 1;
    for (int c = 0; c < (TT - 2) / DPTH; ++c) {
        #pragma unroll
        for (int k = 0; k < DPTH; ++k) {
            float pv[9];
            #pragma unroll
            for (int j = 0; j < 9; ++j) pv[j] = pf[k][j] + EPSF;
            int tp = t + DPTH; if (tp > TT - 1) tp = TT - 1;   // clamped reload
            #pragma unroll
            for (int j = 0; j < 9; ++j)
                pf[k][j] = base[(size_t)tp * CC + zs[j]];
            STEP_BODY(pv);
            ++t;
        }
    }
    { // tail: t = 2046 (pf[0]), t = 2047 (pf[1])
        float pv[9];
        #pragma unroll
        for (int j = 0; j < 9; ++j) pv[j] = pf[0][j] + EPSF;
        STEP_BODY(pv);
        #pragma unroll
        for (int j = 0; j < 9; ++j) pv[j] = pf[1][j] + EPSF;
        STEP_BODY(pv);
    }
#undef STEP_BODY

    // lane 56 holds s=511 (j=7) and s=512 (j=8); single log2 at the end
    if (lane == 56) {
        int E = max(e[7], e[8]);
        const float tot = LDEXP(f[7], e[7] - E) + LDEXP(f[8], e[8] - E);
        const float ll2 = (float)E + __builtin_amdgcn_logf(tot);
        out[b] = -LN2F * ll2;
    }
}

extern "C" void kernel_launch(void* const* d_in, const int* in_sizes, int n_in,
                              void* d_out, int out_size, void* d_ws, size_t ws_size,
                              hipStream_t stream)
{
    const int*   y_true = (const int*)d_in[0];
    const float* y_pred = (const float*)d_in[1];
    float*       out    = (float*)d_out;
    const int B = in_sizes[0] / LL;   // 32
    ctc_ext_kernel<<<B, 64, 0, stream>>>(y_true, y_pred, out);
}

// Round 4
// 464.153 us; speedup vs baseline: 2.0281x; 1.5296x over previous
//
#include <hip/hip_runtime.h>

#define TT   2048
#define CC   256
#define LL   256
#define SS   513            // 2*LL+1
#define EPSF (1e-7f)
#define LN2F (0.69314718055994531f)
#define DPTH 4              // prefetch depth == renorm period
#define RBTH 64             // rebase threshold (bits)

#if __has_builtin(__builtin_amdgcn_frexp_expf)
#define FREXP_EXP __builtin_amdgcn_frexp_expf
#else
static __device__ __forceinline__ int FREXP_EXP(float x){ int e; frexpf(x,&e); return e; }
#endif
#if __has_builtin(__builtin_amdgcn_ldexpf)
#define LDEXP __builtin_amdgcn_ldexpf
#else
#define LDEXP ldexpf
#endif

// One wave per batch. Lane l owns cells s = l*9 + j, j in [0,9).
// All 9 cells share ONE exponent e; value = f[j] * 2^e.
// Per-step update is pure full-rate VALU: 2 add + 2 mul per cell.
// Renorm (max + frexp + 9 ldexp) every DPTH steps keeps f in range.
// Cross-lane boundary (prev lane cells 7,8) aligned via ldexp(., e_prev-e).

__launch_bounds__(64, 1)
__global__ void ctc_shexp_kernel(const int* __restrict__ y_true,
                                 const float* __restrict__ y_pred,
                                 float* __restrict__ out)
{
    const int b     = blockIdx.x;
    const int lane  = threadIdx.x;       // 0..63
    const int blank = CC - 1;

    int   zs[9];
    float kill[9];                        // 1.0 if skip (s-2 -> s) legal
    #pragma unroll
    for (int j = 0; j < 9; ++j) {
        const int s = lane * 9 + j;
        int  z  = blank;
        bool a2 = false;
        if (s < SS && (s & 1)) {
            z = y_true[b * LL + ((s - 1) >> 1)];
            const int zm2 = (s >= 3) ? y_true[b * LL + ((s - 3) >> 1)] : -1;
            a2 = (z != blank) && (z != zm2);
        }
        zs[j]   = z;
        kill[j] = a2 ? 1.0f : 0.0f;
    }

    const float* base = y_pred + (size_t)b * TT * CC;

    // alpha0: cells s<2 get p(t=0)+eps; everything else 0. Lane scale e=0.
    float f[9];
    #pragma unroll
    for (int j = 0; j < 9; ++j) f[j] = 0.0f;
    int e = 0;
    if (lane == 0) {
        f[0] = base[zs[0]] + EPSF;
        f[1] = base[zs[1]] + EPSF;
    }
    // lanes 1..56 start massless (await the activation front); 57..63 are dead
    bool lzero = (lane != 0) && (lane < 57);

    // rolling gather prefetch: pf[k] holds row t = (next consumed + k)
    float pf[DPTH][9];
    #pragma unroll
    for (int k = 0; k < DPTH; ++k)
        #pragma unroll
        for (int j = 0; j < 9; ++j)
            pf[k][j] = base[(size_t)(1 + k) * CC + zs[j]];

#define STEP_BODY(PV) do {                                                    \
        float u8 = __shfl_up(f[8], 1);                                        \
        float u7 = __shfl_up(f[7], 1);                                        \
        int   ue = __shfl_up(e, 1);                                           \
        if (lane == 0) { u8 = 0.0f; u7 = 0.0f; ue = e; }                      \
        int  dlt = ue - e;                                                    \
        bool rb  = lzero || (dlt >= RBTH);                                    \
        if (__ballot(rb)) {  /* rare: activation front / scale jump */        \
            const int sh = rb ? -dlt : 0;                                     \
            _Pragma("unroll")                                                 \
            for (int j = 0; j < 9; ++j) f[j] = LDEXP(f[j], sh);               \
            e     = rb ? ue : e;                                              \
            dlt   = rb ? 0  : dlt;                                            \
            lzero = lzero && (u8 == 0.0f) && (u7 == 0.0f);                    \
        }                                                                     \
        const float bf8 = LDEXP(u8, dlt);                                     \
        const float bf7 = LDEXP(u7, dlt);                                     \
        const float n8 = (f[8] + f[7] + f[6] * kill[8]) * PV[8];              \
        const float n7 = (f[7] + f[6] + f[5] * kill[7]) * PV[7];              \
        const float n6 = (f[6] + f[5] + f[4] * kill[6]) * PV[6];              \
        const float n5 = (f[5] + f[4] + f[3] * kill[5]) * PV[5];              \
        const float n4 = (f[4] + f[3] + f[2] * kill[4]) * PV[4];              \
        const float n3 = (f[3] + f[2] + f[1] * kill[3]) * PV[3];              \
        const float n2 = (f[2] + f[1] + f[0] * kill[2]) * PV[2];              \
        const float n1 = (f[1] + f[0] + bf8 * kill[1]) * PV[1];               \
        const float n0 = (f[0] + bf8  + bf7 * kill[0]) * PV[0];               \
        f[8]=n8; f[7]=n7; f[6]=n6; f[5]=n5; f[4]=n4;                          \
        f[3]=n3; f[2]=n2; f[1]=n1; f[0]=n0;                                   \
    } while (0)

    // main: 511 chunks of 4 steps (t = 1..2044), renorm after each chunk
    int t = 1;
    for (int c = 0; c < (TT - 4) / DPTH; ++c) {
        #pragma unroll
        for (int k = 0; k < DPTH; ++k) {
            float pv[9];
            #pragma unroll
            for (int j = 0; j < 9; ++j) pv[j] = pf[k][j] + EPSF;
            int tp = t + DPTH; if (tp > TT - 1) tp = TT - 1;
            const float* rowp = base + (size_t)tp * CC;
            #pragma unroll
            for (int j = 0; j < 9; ++j) pf[k][j] = rowp[zs[j]];
            STEP_BODY(pv);
            ++t;
        }
        { // renorm: pull lane max back to [0.5,1), fold into e
            float m = fmaxf(fmaxf(fmaxf(f[0], f[1]), fmaxf(f[2], f[3])),
                            fmaxf(fmaxf(f[4], f[5]),
                                  fmaxf(f[6], fmaxf(f[7], f[8]))));
            const int em = FREXP_EXP(m);       // frexp_exp(0) == 0
            #pragma unroll
            for (int j = 0; j < 9; ++j) f[j] = LDEXP(f[j], -em);
            e += em;
        }
    }
    { // tail: t = 2045, 2046, 2047 consume pf[0..2]
        #pragma unroll
        for (int k = 0; k < 3; ++k) {
            float pv[9];
            #pragma unroll
            for (int j = 0; j < 9; ++j) pv[j] = pf[k][j] + EPSF;
            STEP_BODY(pv);
        }
    }
#undef STEP_BODY

    // lane 56 holds s=511 (j=7) and s=512 (j=8); one log2 at the end
    if (lane == 56) {
        const float tot = f[7] + f[8];
        const float ll2 = (float)e + __builtin_amdgcn_logf(tot);
        out[b] = -LN2F * ll2;
    }
}

extern "C" void kernel_launch(void* const* d_in, const int* in_sizes, int n_in,
                              void* d_out, int out_size, void* d_ws, size_t ws_size,
                              hipStream_t stream)
{
    const int*   y_true = (const int*)d_in[0];
    const float* y_pred = (const float*)d_in[1];
    float*       out    = (float*)d_out;
    const int B = in_sizes[0] / LL;   // 32
    ctc_shexp_kernel<<<B, 64, 0, stream>>>(y_true, y_pred, out);
}

// Round 6
// 195.731 us; speedup vs baseline: 4.8093x; 2.3714x over previous
//
#include <hip/hip_runtime.h>

#define TT   2048
#define CC   256
#define LL   256
#define SS   513            // 2*LL+1
#define TM   1023           // meet point: fwd -> alpha[TM], bwd -> gamma[TM+1]
#define EPSF (1e-7f)
#define LN2F (0.69314718055994531f)
#define DPTH 8              // prefetch ring depth (steps ahead)
#define RBTH 64             // rebase threshold (bits)
#define NCH  127            // 127*8 = 1016 steps + 7 tail = 1023
#define EMINI (-2000000000)

#if __has_builtin(__builtin_amdgcn_frexp_expf)
#define FREXP_EXP __builtin_amdgcn_frexp_expf
#else
static __device__ __forceinline__ int FREXP_EXP(float x){ int e; frexpf(x,&e); return e; }
#endif
#if __has_builtin(__builtin_amdgcn_ldexpf)
#define LDEXP __builtin_amdgcn_ldexpf
#else
#define LDEXP ldexpf
#endif

// Block = 128 threads (2 waves) per batch.
//   wave 0: forward alpha DP, rows 1..TM       (init row 0)
//   wave 1: backward gamma DP, rows TT-2..TM+1 (init row TT-1)
// Lane l owns cells s = 8l..8l+7 plus a shadow register f[8] mirroring cell
// 8(l+1) (real cell 512 on lane 63). Even s = blank, odd s = label 4l+i.
// Extended-range floats: value = f[j] * 2^e (one e per lane), renorm every
// 4 steps; cross-lane boundary aligned via ldexp(.., e_nb - e).
// JOIN: per-lane — fwd and bwd use the SAME cell partition, so lane l's
// partial sum needs only bwd lane l's raw mantissas (cw) and exponent (ew).

__launch_bounds__(128, 1)
__global__ void ctc_mim_kernel(const int* __restrict__ y_true,
                               const float* __restrict__ y_pred,
                               float* __restrict__ out)
{
    __shared__ float cw[SS];   // beta[TM][s] combo mantissas (per-lane scale)
    __shared__ int   ew[64];   // bwd per-lane exponent

    const int tid   = threadIdx.x;
    const int w     = tid >> 6;          // 0 = fwd, 1 = bwd (wave-uniform)
    const int lane  = tid & 63;
    const int b     = blockIdx.x;
    const int blank = CC - 1;

    const int*   lab  = y_true + b * LL;
    const float* base = y_pred + (size_t)b * TT * CC;

    // label columns for odd cells j = 2i+1 (label index 4*lane + i)
    int   col[4];
    float kup[4];    // fwd skip legality into cell s (allow2[s])
    float kdn[4];    // bwd skip legality out of cell s (allow2[s+2])
    #pragma unroll
    for (int i = 0; i < 4; ++i) {
        const int li = 4 * lane + i;               // 0..255
        const int z  = lab[li];
        col[i] = z;
        const int zm = (li >= 1) ? lab[li - 1] : -1;
        kup[i] = (z != zm) ? 1.0f : 0.0f;
        kdn[i] = (li <= 254 && lab[li + 1] != z) ? 1.0f : 0.0f;
    }

    float f[9];
    #pragma unroll
    for (int j = 0; j < 9; ++j) f[j] = 0.0f;
    int  e = 0;
    bool lzero;

    if (w == 0) {
        if (lane == 0) {
            f[0] = base[blank]  + EPSF;            // s=0, t=0
            f[1] = base[col[0]] + EPSF;            // s=1, t=0
        }
        lzero = (lane != 0);
    } else {
        if (lane == 63) {
            const float* rT = base + (size_t)(TT - 1) * CC;
            f[7] = rT[col[3]] + EPSF;              // s=511, t=TT-1
            f[8] = rT[blank]  + EPSF;              // s=512 (shadow), t=TT-1
        }
        lzero = (lane != 63);
    }

    // prefetch ring: pfb = blank column, pfl = 4 label columns
    float pfb[DPTH];
    float pfl[DPTH][4];
    #pragma unroll
    for (int k = 0; k < DPTH; ++k) {
        const int r = (w == 0) ? (1 + k) : (TT - 2 - k);
        const float* rp = base + (size_t)r * CC;
        pfb[k] = rp[blank];
        #pragma unroll
        for (int i = 0; i < 4; ++i) pfl[k][i] = rp[col[i]];
    }

    auto renorm = [&]() {
        float m = fmaxf(fmaxf(fmaxf(f[0], f[1]), fmaxf(f[2], f[3])),
                        fmaxf(fmaxf(f[4], f[5]), fmaxf(f[6], fmaxf(f[7], f[8]))));
        const int em = FREXP_EXP(m);               // frexp_exp(0) == 0
        #pragma unroll
        for (int j = 0; j < 9; ++j) f[j] = LDEXP(f[j], -em);
        e += em;
    };

    auto fwd_step = [&](float pb, float p0, float p1, float p2, float p3) {
        float u7 = __shfl_up(f[7], 1);
        int   ue = __shfl_up(e, 1);
        if (lane == 0) { u7 = 0.0f; ue = e; }
        int dlt = ue - e;
        const bool rb = lzero || (dlt >= RBTH);
        if (__ballot(rb)) {                        // rare: front / scale jump
            const int sh = rb ? -dlt : 0;
            #pragma unroll
            for (int j = 0; j < 9; ++j) f[j] = LDEXP(f[j], sh);
            e   = rb ? ue : e;
            dlt = rb ? 0  : dlt;
            lzero = lzero && (u7 == 0.0f);
        }
        const float bf = LDEXP(u7, dlt);
        const float n0 = (f[0] + bf) * pb;
        const float n1 = (f[1] + f[0] + bf   * kup[0]) * p0;
        const float n2 = (f[2] + f[1]) * pb;
        const float n3 = (f[3] + f[2] + f[1] * kup[1]) * p1;
        const float n4 = (f[4] + f[3]) * pb;
        const float n5 = (f[5] + f[4] + f[3] * kup[2]) * p2;
        const float n6 = (f[6] + f[5]) * pb;
        const float n7 = (f[7] + f[6] + f[5] * kup[3]) * p3;
        const float n8 = (f[8] + f[7]) * pb;
        f[0]=n0; f[1]=n1; f[2]=n2; f[3]=n3; f[4]=n4;
        f[5]=n5; f[6]=n6; f[7]=n7; f[8]=n8;
    };

    auto bwd_step = [&](float pb, float p0, float p1, float p2, float p3) {
        float d1 = __shfl_down(f[1], 1);
        int   de = __shfl_down(e, 1);
        if (lane == 63) { d1 = 0.0f; de = e; }
        int dlt = de - e;
        const bool rb = lzero || (dlt >= RBTH);
        if (__ballot(rb)) {
            const int sh = rb ? -dlt : 0;
            #pragma unroll
            for (int j = 0; j < 9; ++j) f[j] = LDEXP(f[j], sh);
            e   = rb ? de : e;
            dlt = rb ? 0  : dlt;
            lzero = lzero && (d1 == 0.0f);
        }
        const float bf = LDEXP(d1, dlt);
        const float n0 = (f[0] + f[1]) * pb;
        const float n1 = (f[1] + f[2] + f[3] * kdn[0]) * p0;
        const float n2 = (f[2] + f[3]) * pb;
        const float n3 = (f[3] + f[4] + f[5] * kdn[1]) * p1;
        const float n4 = (f[4] + f[5]) * pb;
        const float n5 = (f[5] + f[6] + f[7] * kdn[2]) * p2;
        const float n6 = (f[6] + f[7]) * pb;
        const float n7 = (f[7] + f[8] + bf   * kdn[3]) * p3;
        const float n8 = (f[8] + bf) * pb;
        f[0]=n0; f[1]=n1; f[2]=n2; f[3]=n3; f[4]=n4;
        f[5]=n5; f[6]=n6; f[7]=n7; f[8]=n8;
    };

    if (w == 0) {
        for (int c = 0; c < NCH; ++c) {
            #pragma unroll
            for (int k = 0; k < DPTH; ++k) {
                const float pb = pfb[k]    + EPSF;
                const float p0 = pfl[k][0] + EPSF;
                const float p1 = pfl[k][1] + EPSF;
                const float p2 = pfl[k][2] + EPSF;
                const float p3 = pfl[k][3] + EPSF;
                int tp = 1 + c * DPTH + k + DPTH; if (tp > TM) tp = TM;
                const float* rp = base + (size_t)tp * CC;
                pfb[k] = rp[blank];
                #pragma unroll
                for (int i = 0; i < 4; ++i) pfl[k][i] = rp[col[i]];
                fwd_step(pb, p0, p1, p2, p3);
                if (k == 3 || k == 7) renorm();
            }
        }
        #pragma unroll
        for (int k = 0; k < 7; ++k) {
            fwd_step(pfb[k] + EPSF, pfl[k][0] + EPSF, pfl[k][1] + EPSF,
                     pfl[k][2] + EPSF, pfl[k][3] + EPSF);
            if (k == 3) renorm();
        }
    } else {
        for (int c = 0; c < NCH; ++c) {
            #pragma unroll
            for (int k = 0; k < DPTH; ++k) {
                const float pb = pfb[k]    + EPSF;
                const float p0 = pfl[k][0] + EPSF;
                const float p1 = pfl[k][1] + EPSF;
                const float p2 = pfl[k][2] + EPSF;
                const float p3 = pfl[k][3] + EPSF;
                int tp = (TT - 2) - (c * DPTH + k) - DPTH; if (tp < TM + 1) tp = TM + 1;
                const float* rp = base + (size_t)tp * CC;
                pfb[k] = rp[blank];
                #pragma unroll
                for (int i = 0; i < 4; ++i) pfl[k][i] = rp[col[i]];
                bwd_step(pb, p0, p1, p2, p3);
                if (k == 3 || k == 7) renorm();
            }
        }
        #pragma unroll
        for (int k = 0; k < 7; ++k) {
            bwd_step(pfb[k] + EPSF, pfl[k][0] + EPSF, pfl[k][1] + EPSF,
                     pfl[k][2] + EPSF, pfl[k][3] + EPSF);
            if (k == 3) renorm();
        }

        // combo: beta[TM][s] = g[s] + g[s+1] + allow2[s+2]*g[s+2] (no p mult)
        float d1 = __shfl_down(f[1], 1);
        int   de = __shfl_down(e, 1);
        if (lane == 63) { d1 = 0.0f; de = e; }
        int dlt = de - e;
        if (dlt >= RBTH) {                         // one-shot, per-lane safe
            #pragma unroll
            for (int j = 0; j < 9; ++j) f[j] = LDEXP(f[j], -dlt);
            e = de; dlt = 0;
        }
        const float bf = LDEXP(d1, dlt);
        float cb[9];
        cb[0] = f[0] + f[1];
        cb[1] = f[1] + f[2] + f[3] * kdn[0];
        cb[2] = f[2] + f[3];
        cb[3] = f[3] + f[4] + f[5] * kdn[1];
        cb[4] = f[4] + f[5];
        cb[5] = f[5] + f[6] + f[7] * kdn[2];
        cb[6] = f[6] + f[7];
        cb[7] = f[7] + f[8] + bf   * kdn[3];
        cb[8] = f[8] + bf;                          // combo[512] (lane 63: bf=0)

        // per-lane join data: raw mantissas + this lane's exponent.
        #pragma unroll
        for (int j = 0; j < 8; ++j) cw[8 * lane + j] = cb[j];
        if (lane == 63) cw[512] = cb[8];
        ew[lane] = e;
    }

    __syncthreads();

    if (w == 0) {
        // lane l's 8 cells align exactly with bwd lane l's 8 cells:
        // part(l) = sum_j alpha_mant[j] * beta_mant[8l+j], scale 2^(e + ew[l])
        float part = 0.0f;
        #pragma unroll
        for (int j = 0; j < 8; ++j) part += f[j] * cw[8 * lane + j];
        if (lane == 63) part += f[8] * cw[512];
        int   ep = (part > 0.0f) ? (e + ew[lane]) : EMINI;
        float m  = part;
        #pragma unroll
        for (int d = 1; d < 64; d <<= 1) {
            const float mo = __shfl_xor(m, d);
            const int   eo = __shfl_xor(ep, d);
            const int   E  = max(ep, eo);
            m  = LDEXP(m, ep - E) + LDEXP(mo, eo - E);
            ep = E;
        }
        if (lane == 0)
            out[b] = -LN2F * ((float)ep + __builtin_amdgcn_logf(m));
    }
}

extern "C" void kernel_launch(void* const* d_in, const int* in_sizes, int n_in,
                              void* d_out, int out_size, void* d_ws, size_t ws_size,
                              hipStream_t stream)
{
    const int*   y_true = (const int*)d_in[0];
    const float* y_pred = (const float*)d_in[1];
    float*       out    = (float*)d_out;
    const int B = in_sizes[0] / LL;   // 32
    ctc_mim_kernel<<<B, 128, 0, stream>>>(y_true, y_pred, out);
}